// Round 16
// baseline (24933.136 us; speedup 1.0000x reference)
//
#include <hip/hip_runtime.h>

#define L_DIM 1024
#define B_DIM 128
#define I_DIM 256
#define H_DIM 512

typedef unsigned short u16x8 __attribute__((ext_vector_type(8)));
typedef __bf16 bf16x8 __attribute__((ext_vector_type(8)));
typedef float f32x4 __attribute__((ext_vector_type(4)));
typedef unsigned long long u64;
typedef unsigned int u32;

static __device__ __forceinline__ unsigned short f2bf(float f) {
  unsigned u = __builtin_bit_cast(unsigned, f);
  u += 0x7FFFu + ((u >> 16) & 1u);
  return (unsigned short)(u >> 16);
}
static __device__ __forceinline__ float bf2f(unsigned short b) {
  return __builtin_bit_cast(float, ((unsigned)b) << 16);
}
static __device__ __forceinline__ bf16x8 ld_frag_g(const unsigned short* p, size_t idx8) {
  return __builtin_bit_cast(bf16x8, reinterpret_cast<const u16x8*>(p)[idx8]);
}

// ---------------------------------------------------------------------------
// Pack Wx and Wh into MFMA B-fragment order, split hi/lo bf16. (unchanged)
// ---------------------------------------------------------------------------
__global__ void pack_weights(const float* __restrict__ Wx, const float* __restrict__ Wh,
                             unsigned short* __restrict__ WxHi, unsigned short* __restrict__ WxLo,
                             unsigned short* __restrict__ WhHi, unsigned short* __restrict__ WhLo) {
  int tid = blockIdx.x * blockDim.x + threadIdx.x;
  if (tid < 32 * 8 * 64) {
    int lane = tid & 63, kt = (tid >> 6) & 7, nt = tid >> 9;
    int n = nt * 16 + (lane & 15), k0 = kt * 32 + (lane >> 4) * 8;
    const float* src = Wx + (size_t)n * I_DIM + k0;
    #pragma unroll
    for (int j = 0; j < 8; ++j) {
      float v = src[j];
      unsigned short hb = f2bf(v);
      WxHi[(size_t)tid * 8 + j] = hb;
      WxLo[(size_t)tid * 8 + j] = f2bf(v - bf2f(hb));
    }
  }
  if (tid < 32 * 16 * 64) {
    int lane = tid & 63, kt = (tid >> 6) & 15, nt = tid >> 10;
    int n = nt * 16 + (lane & 15), k0 = kt * 32 + (lane >> 4) * 8;
    const float* src = Wh + (size_t)n * H_DIM + k0;
    #pragma unroll
    for (int j = 0; j < 8; ++j) {
      float v = src[j];
      unsigned short hb = f2bf(v);
      WhHi[(size_t)tid * 8 + j] = hb;
      WhLo[(size_t)tid * 8 + j] = f2bf(v - bf2f(hb));
    }
  }
}

// ---------------------------------------------------------------------------
// xproj (unchanged)
// ---------------------------------------------------------------------------
__global__ __launch_bounds__(256) void xproj_kernel(const float* __restrict__ x,
    const unsigned short* __restrict__ WxHi, const unsigned short* __restrict__ WxLo,
    const float* __restrict__ bh, float* __restrict__ out) {
  __shared__ unsigned short ahi[128][40];
  __shared__ unsigned short alo[128][40];
  const int tid = threadIdx.x, lane = tid & 63, wid = tid >> 6;
  const int mbase = blockIdx.x * 128, cbase = blockIdx.y * 128;
  const int wrow = (wid >> 1) * 64, wcol = (wid & 1) * 64;
  f32x4 acc[4][4] = {};
  const int srow = tid >> 1, shalf = (tid & 1) * 16;

  for (int kt = 0; kt < 8; ++kt) {
    const f32x4* src = reinterpret_cast<const f32x4*>(
        x + (size_t)(mbase + srow) * I_DIM + kt * 32 + shalf);
    f32x4 v[4];
    v[0] = src[0]; v[1] = src[1]; v[2] = src[2]; v[3] = src[3];
    u16x8 hh[2], ll[2];
    #pragma unroll
    for (int q = 0; q < 2; ++q) {
      #pragma unroll
      for (int e = 0; e < 8; ++e) {
        float f = v[q * 2 + (e >> 2)][e & 3];
        unsigned short hb = f2bf(f);
        hh[q][e] = hb;
        ll[q][e] = f2bf(f - bf2f(hb));
      }
    }
    __syncthreads();
    *reinterpret_cast<u16x8*>(&ahi[srow][shalf]) = hh[0];
    *reinterpret_cast<u16x8*>(&ahi[srow][shalf + 8]) = hh[1];
    *reinterpret_cast<u16x8*>(&alo[srow][shalf]) = ll[0];
    *reinterpret_cast<u16x8*>(&alo[srow][shalf + 8]) = ll[1];
    __syncthreads();

    bf16x8 amh[4], aml[4];
    #pragma unroll
    for (int m = 0; m < 4; ++m) {
      amh[m] = __builtin_bit_cast(bf16x8, *reinterpret_cast<const u16x8*>(
          &ahi[wrow + m * 16 + (lane & 15)][(lane >> 4) * 8]));
      aml[m] = __builtin_bit_cast(bf16x8, *reinterpret_cast<const u16x8*>(
          &alo[wrow + m * 16 + (lane & 15)][(lane >> 4) * 8]));
    }
    bf16x8 bhh[4], bll[4];
    #pragma unroll
    for (int n = 0; n < 4; ++n) {
      int ntg = (cbase + wcol) / 16 + n;
      size_t idx = (size_t)(ntg * 8 + kt) * 64 + lane;
      bhh[n] = ld_frag_g(WxHi, idx);
      bll[n] = ld_frag_g(WxLo, idx);
    }
    #pragma unroll
    for (int m = 0; m < 4; ++m) {
      #pragma unroll
      for (int n = 0; n < 4; ++n) {
        acc[m][n] = __builtin_amdgcn_mfma_f32_16x16x32_bf16(amh[m], bhh[n], acc[m][n], 0, 0, 0);
        acc[m][n] = __builtin_amdgcn_mfma_f32_16x16x32_bf16(aml[m], bhh[n], acc[m][n], 0, 0, 0);
        acc[m][n] = __builtin_amdgcn_mfma_f32_16x16x32_bf16(amh[m], bll[n], acc[m][n], 0, 0, 0);
      }
    }
  }

  #pragma unroll
  for (int n = 0; n < 4; ++n) {
    int col = cbase + wcol + n * 16 + (lane & 15);
    float bv = bh[col];
    #pragma unroll
    for (int m = 0; m < 4; ++m) {
      int rg = mbase + wrow + m * 16 + ((lane >> 4) << 2);
      #pragma unroll
      for (int r = 0; r < 4; ++r)
        out[(size_t)(rg + r) * H_DIM + col] = acc[m][n][r] + bv;
    }
  }
}

// ---------------------------------------------------------------------------
// Recurrence: 8 WGs x 1024 thr (16 waves) — ONE WG PER BATCH-GROUP.
// g = blockIdx.x owns batch rows g*16..+15, ALL 512 output cols.
// Wave w (0..15) owns cols w*32..w*32+31 (2 col-tiles); Wh hi/lo fragments
// for both tiles live in 256 VGPRs. h_t in double-buffered LDS hb[2].
// NO cross-WG exchange: h_{t+1} is written to LDS and published by ONE
// s_barrier per step (lgkmcnt only — out-stores/xp-loads stay in flight).
// This deletes the 3-fabric-RTT chain (~5.5k cy/step) of R2..R15 entirely.
// Double-buffer safety (R15-proven argument): step-t writes target
// hb[(t+1)&1]; all reads of that buffer (step t-1 MFMA) completed before
// the end-of-(t-1) barrier.
// ---------------------------------------------------------------------------
__global__ __launch_bounds__(1024, 4) void rnn_kernel(const float* __restrict__ h0,
    const unsigned short* __restrict__ WhHi, const unsigned short* __restrict__ WhLo,
    float* __restrict__ out) {
  __shared__ __attribute__((aligned(16))) unsigned short hb[2][16 * 520];
  const int tid = threadIdx.x, lane = tid & 63, w = tid >> 6;  // w: 0..15
  const int g = blockIdx.x;

  // ---- one-time: Wh fragments for both col-tiles -> VGPRs ----
  bf16x8 wfh0[16], wfl0[16], wfh1[16], wfl1[16];
  #pragma unroll
  for (int kt = 0; kt < 16; ++kt) {
    size_t i0 = (size_t)((w * 2 + 0) * 16 + kt) * 64 + lane;
    size_t i1 = (size_t)((w * 2 + 1) * 16 + kt) * 64 + lane;
    wfh0[kt] = ld_frag_g(WhHi, i0);
    wfl0[kt] = ld_frag_g(WhLo, i0);
    wfh1[kt] = ld_frag_g(WhHi, i1);
    wfl1[kt] = ld_frag_g(WhLo, i1);
  }

  // ---- one-time: h0 -> hb[0] bf16 (1024 threads, 8 elems each) ----
  {
    int row = tid >> 6, col0 = (tid & 63) * 8;
    const f32x4* s = reinterpret_cast<const f32x4*>(
        h0 + (size_t)(g * 16 + row) * H_DIM + col0);
    f32x4 v0 = s[0], v1 = s[1];
    u16x8 hv;
    #pragma unroll
    for (int e = 0; e < 4; ++e) { hv[e] = f2bf(v0[e]); hv[4 + e] = f2bf(v1[e]); }
    *reinterpret_cast<u16x8*>(&hb[0][row * 520 + col0]) = hv;
  }
  __syncthreads();

  const int arow = lane & 15;        // A row (batch); D col within 16
  const int aoff = (lane >> 4) * 8;  // A k offset (elements)
  const int drow = (lane >> 4) * 4;  // D row base
  const int col0 = w * 32 + (lane & 15);       // tile-0 output col
  const int col1 = col0 + 16;                  // tile-1 output col

  // ---- xp pipeline depth 2 ----
  f32x4 xpA0, xpA1, xpB0, xpB1;
  #pragma unroll
  for (int r = 0; r < 4; ++r) {
    size_t rw = (size_t)(g * 16 + drow + r) * H_DIM;
    xpA0[r] = out[rw + col0];
    xpA1[r] = out[rw + col1];
    xpB0[r] = out[(size_t)B_DIM * H_DIM + rw + col0];
    xpB1[r] = out[(size_t)B_DIM * H_DIM + rw + col1];
  }

  for (int t = 0; t < L_DIM; ++t) {
    const size_t obase = ((size_t)t * B_DIM + g * 16) * H_DIM;
    const int cur = t & 1;

    // ---- z = h_t . Wh (hi+lo), 2 col-tiles: 64 MFMAs, 8 chains ----
    f32x4 c0h = {}, c0l = {}, c1h = {}, c1l = {};
    f32x4 d0h = {}, d0l = {}, d1h = {}, d1l = {};
    #pragma unroll
    for (int kt = 0; kt < 16; kt += 2) {
      bf16x8 af0 = __builtin_bit_cast(bf16x8, *reinterpret_cast<const u16x8*>(
          &hb[cur][arow * 520 + kt * 32 + aoff]));
      bf16x8 af1 = __builtin_bit_cast(bf16x8, *reinterpret_cast<const u16x8*>(
          &hb[cur][arow * 520 + (kt + 1) * 32 + aoff]));
      c0h = __builtin_amdgcn_mfma_f32_16x16x32_bf16(af0, wfh0[kt], c0h, 0, 0, 0);
      c0l = __builtin_amdgcn_mfma_f32_16x16x32_bf16(af0, wfl0[kt], c0l, 0, 0, 0);
      c1h = __builtin_amdgcn_mfma_f32_16x16x32_bf16(af0, wfh1[kt], c1h, 0, 0, 0);
      c1l = __builtin_amdgcn_mfma_f32_16x16x32_bf16(af0, wfl1[kt], c1l, 0, 0, 0);
      d0h = __builtin_amdgcn_mfma_f32_16x16x32_bf16(af1, wfh0[kt + 1], d0h, 0, 0, 0);
      d0l = __builtin_amdgcn_mfma_f32_16x16x32_bf16(af1, wfl0[kt + 1], d0l, 0, 0, 0);
      d1h = __builtin_amdgcn_mfma_f32_16x16x32_bf16(af1, wfh1[kt + 1], d1h, 0, 0, 0);
      d1l = __builtin_amdgcn_mfma_f32_16x16x32_bf16(af1, wfl1[kt + 1], d1l, 0, 0, 0);
    }

    float hv0[4], hv1[4];
    unsigned short hu0[4], hu1[4];
    #pragma unroll
    for (int r = 0; r < 4; ++r) {
      float z0 = c0h[r] + c0l[r] + d0h[r] + d0l[r] + xpA0[r];
      float z1 = c1h[r] + c1l[r] + d1h[r] + d1l[r] + xpA1[r];
      float e0 = __expf(2.0f * z0);
      float e1 = __expf(2.0f * z1);
      hv0[r] = 1.0f - 2.0f / (e0 + 1.0f);  // tanh(z0)
      hv1[r] = 1.0f - 2.0f / (e1 + 1.0f);  // tanh(z1)
      hu0[r] = f2bf(hv0[r]);
      hu1[r] = f2bf(hv1[r]);
    }

    // ---- out stores (fire-and-forget; drain across steps) ----
    #pragma unroll
    for (int r = 0; r < 4; ++r) {
      out[obase + (size_t)(drow + r) * H_DIM + col0] = hv0[r];
      out[obase + (size_t)(drow + r) * H_DIM + col1] = hv1[r];
    }
    if (t == L_DIM - 1) break;

    const int buf = (t + 1) & 1;

    // ---- h_{t+1} into LDS (own 2 col-tiles; no pre-barrier needed) ----
    #pragma unroll
    for (int r = 0; r < 4; ++r) {
      hb[buf][(drow + r) * 520 + col0] = hu0[r];
      hb[buf][(drow + r) * 520 + col1] = hu1[r];
    }

    // ---- xp pipeline advance (t+2) ----
    xpA0 = xpB0; xpA1 = xpB1;
    {
      const int tn = (t + 2 < L_DIM) ? t + 2 : L_DIM - 1;
      const size_t obn = ((size_t)tn * B_DIM + g * 16) * H_DIM;
      #pragma unroll
      for (int r = 0; r < 4; ++r) {
        xpB0[r] = out[obn + (size_t)(drow + r) * H_DIM + col0];
        xpB1[r] = out[obn + (size_t)(drow + r) * H_DIM + col1];
      }
    }

    // ---- publish step: LDS writes drained, one barrier (no vmcnt drain) ----
    __builtin_amdgcn_sched_barrier(0);
    asm volatile("s_waitcnt lgkmcnt(0)" ::: "memory");
    __builtin_amdgcn_sched_barrier(0);
    __builtin_amdgcn_s_barrier();      // hb[buf] = h_{t+1} WG-wide
    __builtin_amdgcn_sched_barrier(0);
  }
}

extern "C" void kernel_launch(void* const* d_in, const int* in_sizes, int n_in,
                              void* d_out, int out_size, void* d_ws, size_t ws_size,
                              hipStream_t stream) {
  (void)in_sizes; (void)n_in; (void)out_size; (void)ws_size;
  const float* x  = (const float*)d_in[0];
  const float* h0 = (const float*)d_in[1];
  const float* Wx = (const float*)d_in[2];
  const float* Wh = (const float*)d_in[3];
  const float* bh = (const float*)d_in[4];
  float* out = (float*)d_out;

  unsigned short* WxHi = (unsigned short*)d_ws;       // 131072 u16
  unsigned short* WxLo = WxHi + 131072;               // 131072 u16
  unsigned short* WhHi = WxLo + 131072;               // 262144 u16
  unsigned short* WhLo = WhHi + 262144;               // 262144 u16 (ends 1572864 B)

  hipLaunchKernelGGL(pack_weights, dim3(128), dim3(256), 0, stream,
                     Wx, Wh, WxHi, WxLo, WhHi, WhLo);
  hipLaunchKernelGGL(xproj_kernel, dim3(1024, 4), dim3(256), 0, stream,
                     x, WxHi, WxLo, bh, out);
  hipLaunchKernelGGL(rnn_kernel, dim3(8), dim3(1024), 0, stream,
                     h0, WhHi, WhLo, out);
}

// Round 17
// 6889.509 us; speedup vs baseline: 3.6190x; 3.6190x over previous
//
#include <hip/hip_runtime.h>

#define L_DIM 1024
#define B_DIM 128
#define I_DIM 256
#define H_DIM 512

typedef unsigned short u16x8 __attribute__((ext_vector_type(8)));
typedef __bf16 bf16x8 __attribute__((ext_vector_type(8)));
typedef float f32x4 __attribute__((ext_vector_type(4)));
typedef unsigned long long u64;
typedef unsigned int u32;

static __device__ __forceinline__ unsigned short f2bf(float f) {
  unsigned u = __builtin_bit_cast(unsigned, f);
  u += 0x7FFFu + ((u >> 16) & 1u);
  return (unsigned short)(u >> 16);
}
static __device__ __forceinline__ float bf2f(unsigned short b) {
  return __builtin_bit_cast(float, ((unsigned)b) << 16);
}
static __device__ __forceinline__ bf16x8 ld_frag_g(const unsigned short* p, size_t idx8) {
  return __builtin_bit_cast(bf16x8, reinterpret_cast<const u16x8*>(p)[idx8]);
}

// ---------------------------------------------------------------------------
// Pack Wx and Wh into MFMA B-fragment order, split hi/lo bf16. (unchanged)
// ---------------------------------------------------------------------------
__global__ void pack_weights(const float* __restrict__ Wx, const float* __restrict__ Wh,
                             unsigned short* __restrict__ WxHi, unsigned short* __restrict__ WxLo,
                             unsigned short* __restrict__ WhHi, unsigned short* __restrict__ WhLo) {
  int tid = blockIdx.x * blockDim.x + threadIdx.x;
  if (tid < 32 * 8 * 64) {
    int lane = tid & 63, kt = (tid >> 6) & 7, nt = tid >> 9;
    int n = nt * 16 + (lane & 15), k0 = kt * 32 + (lane >> 4) * 8;
    const float* src = Wx + (size_t)n * I_DIM + k0;
    #pragma unroll
    for (int j = 0; j < 8; ++j) {
      float v = src[j];
      unsigned short hb = f2bf(v);
      WxHi[(size_t)tid * 8 + j] = hb;
      WxLo[(size_t)tid * 8 + j] = f2bf(v - bf2f(hb));
    }
  }
  if (tid < 32 * 16 * 64) {
    int lane = tid & 63, kt = (tid >> 6) & 15, nt = tid >> 10;
    int n = nt * 16 + (lane & 15), k0 = kt * 32 + (lane >> 4) * 8;
    const float* src = Wh + (size_t)n * H_DIM + k0;
    #pragma unroll
    for (int j = 0; j < 8; ++j) {
      float v = src[j];
      unsigned short hb = f2bf(v);
      WhHi[(size_t)tid * 8 + j] = hb;
      WhLo[(size_t)tid * 8 + j] = f2bf(v - bf2f(hb));
    }
  }
}

// ---------------------------------------------------------------------------
// xproj (unchanged)
// ---------------------------------------------------------------------------
__global__ __launch_bounds__(256) void xproj_kernel(const float* __restrict__ x,
    const unsigned short* __restrict__ WxHi, const unsigned short* __restrict__ WxLo,
    const float* __restrict__ bh, float* __restrict__ out) {
  __shared__ unsigned short ahi[128][40];
  __shared__ unsigned short alo[128][40];
  const int tid = threadIdx.x, lane = tid & 63, wid = tid >> 6;
  const int mbase = blockIdx.x * 128, cbase = blockIdx.y * 128;
  const int wrow = (wid >> 1) * 64, wcol = (wid & 1) * 64;
  f32x4 acc[4][4] = {};
  const int srow = tid >> 1, shalf = (tid & 1) * 16;

  for (int kt = 0; kt < 8; ++kt) {
    const f32x4* src = reinterpret_cast<const f32x4*>(
        x + (size_t)(mbase + srow) * I_DIM + kt * 32 + shalf);
    f32x4 v[4];
    v[0] = src[0]; v[1] = src[1]; v[2] = src[2]; v[3] = src[3];
    u16x8 hh[2], ll[2];
    #pragma unroll
    for (int q = 0; q < 2; ++q) {
      #pragma unroll
      for (int e = 0; e < 8; ++e) {
        float f = v[q * 2 + (e >> 2)][e & 3];
        unsigned short hb = f2bf(f);
        hh[q][e] = hb;
        ll[q][e] = f2bf(f - bf2f(hb));
      }
    }
    __syncthreads();
    *reinterpret_cast<u16x8*>(&ahi[srow][shalf]) = hh[0];
    *reinterpret_cast<u16x8*>(&ahi[srow][shalf + 8]) = hh[1];
    *reinterpret_cast<u16x8*>(&alo[srow][shalf]) = ll[0];
    *reinterpret_cast<u16x8*>(&alo[srow][shalf + 8]) = ll[1];
    __syncthreads();

    bf16x8 amh[4], aml[4];
    #pragma unroll
    for (int m = 0; m < 4; ++m) {
      amh[m] = __builtin_bit_cast(bf16x8, *reinterpret_cast<const u16x8*>(
          &ahi[wrow + m * 16 + (lane & 15)][(lane >> 4) * 8]));
      aml[m] = __builtin_bit_cast(bf16x8, *reinterpret_cast<const u16x8*>(
          &alo[wrow + m * 16 + (lane & 15)][(lane >> 4) * 8]));
    }
    bf16x8 bhh[4], bll[4];
    #pragma unroll
    for (int n = 0; n < 4; ++n) {
      int ntg = (cbase + wcol) / 16 + n;
      size_t idx = (size_t)(ntg * 8 + kt) * 64 + lane;
      bhh[n] = ld_frag_g(WxHi, idx);
      bll[n] = ld_frag_g(WxLo, idx);
    }
    #pragma unroll
    for (int m = 0; m < 4; ++m) {
      #pragma unroll
      for (int n = 0; n < 4; ++n) {
        acc[m][n] = __builtin_amdgcn_mfma_f32_16x16x32_bf16(amh[m], bhh[n], acc[m][n], 0, 0, 0);
        acc[m][n] = __builtin_amdgcn_mfma_f32_16x16x32_bf16(aml[m], bhh[n], acc[m][n], 0, 0, 0);
        acc[m][n] = __builtin_amdgcn_mfma_f32_16x16x32_bf16(amh[m], bll[n], acc[m][n], 0, 0, 0);
      }
    }
  }

  #pragma unroll
  for (int n = 0; n < 4; ++n) {
    int col = cbase + wcol + n * 16 + (lane & 15);
    float bv = bh[col];
    #pragma unroll
    for (int m = 0; m < 4; ++m) {
      int rg = mbase + wrow + m * 16 + ((lane >> 4) << 2);
      #pragma unroll
      for (int r = 0; r < 4; ++r)
        out[(size_t)(rg + r) * H_DIM + col] = acc[m][n][r] + bv;
    }
  }
}

// ---------------------------------------------------------------------------
// Recurrence: 16 WGs x 256 thr (4 waves). blockIdx.x = gh*8 + c:
//   c = col-range (64 cols, wave w owns col-tile c*4+w, 16 cols);
//   gh = group-half; this WG processes FOUR independent batch-groups
//   g = gh*4+q (q=0..3), 16 rows each.
// Rationale: the cross-CU exchange chain (~3 fabric RTTs ~5k cy) is an
// irreducible latency (R2-R15), but the 8 recurrences are independent —
// interleaving 4 per WG hides the chain under the other groups' compute.
// Per superstep t: compute+publish q0..q3 -> ONE vmcnt(0) ack -> 4 tags ->
// xp(t+2) prefetch -> 28-lane parallel poll (lane l: group l/7, peer l%7)
// -> per-q pull 7 u64 + scatter -> lgkmcnt -> ONE s_barrier.
// Per-group protocol/layout byte-identical to R15 (proven live + race-free).
// LDS: 4 groups x double-buffered [16][520] bf16 = 133,120 B (dynamic).
// ---------------------------------------------------------------------------
__global__ __launch_bounds__(256, 1) void rnn_kernel(const float* __restrict__ h0,
    const unsigned short* __restrict__ WhHi, const unsigned short* __restrict__ WhLo,
    u32* __restrict__ tags, u64* __restrict__ gbuf,
    float* __restrict__ out) {
  extern __shared__ __attribute__((aligned(16))) unsigned short hb[];  // [4][2][16*520]
  const int HB = 16 * 520;
  const int tid = threadIdx.x, lane = tid & 63, w = tid >> 6;
  const int c = blockIdx.x & 7;    // col-range
  const int gh = blockIdx.x >> 3;  // group half (0..1)

  // ---- one-time: Wh fragments -> VGPRs (16 cols x 512 k, hi+lo) ----
  bf16x8 wfh[16], wfl[16];
  #pragma unroll
  for (int kt = 0; kt < 16; ++kt) {
    size_t idx = (size_t)((c * 4 + w) * 16 + kt) * 64 + lane;
    wfh[kt] = ld_frag_g(WhHi, idx);
    wfl[kt] = ld_frag_g(WhLo, idx);
  }

  const int arow = lane & 15;        // A row (batch); D col within 16
  const int aoff = (lane >> 4) * 8;  // A k offset
  const int drow = (lane >> 4) * 4;  // D row base
  const int gcol = c * 64 + w * 16 + (lane & 15);
  const int pslot = (w * 16 + (lane & 15)) * 4 + (lane >> 4);
  const int ccol = tid >> 2;
  const int crow0 = (tid & 3) * 4;

  // ---- one-time: h0 -> hb[q][0] bf16 (thread: row tid>>4, 32 cols) ----
  {
    int row = tid >> 4, cb = (tid & 15) * 32;
    #pragma unroll
    for (int q = 0; q < 4; ++q) {
      const f32x4* s = reinterpret_cast<const f32x4*>(
          h0 + (size_t)((gh * 4 + q) * 16 + row) * H_DIM + cb);
      #pragma unroll
      for (int u = 0; u < 4; ++u) {
        f32x4 v0 = s[2 * u], v1 = s[2 * u + 1];
        u16x8 hv;
        #pragma unroll
        for (int e = 0; e < 4; ++e) { hv[e] = f2bf(v0[e]); hv[4 + e] = f2bf(v1[e]); }
        *reinterpret_cast<u16x8*>(&hb[(q * 2) * HB + row * 520 + cb + u * 8]) = hv;
      }
    }
  }
  __syncthreads();

  // ---- xp pipeline depth 2 (per group) ----
  f32x4 xpA[4], xpB[4];
  #pragma unroll
  for (int q = 0; q < 4; ++q) {
    #pragma unroll
    for (int r = 0; r < 4; ++r) {
      size_t rw = (size_t)((gh * 4 + q) * 16 + drow + r) * H_DIM + gcol;
      xpA[q][r] = out[rw];
      xpB[q][r] = out[(size_t)B_DIM * H_DIM + rw];
    }
  }

  for (int t = 0; t < L_DIM; ++t) {
    const int cur = t & 1, nxt = cur ^ 1;
    const unsigned step = (unsigned)(t + 1);
    const unsigned buf = step & 1;

    // ---- phase 1: compute + out-store + publish + own-slice, q0..q3 ----
    #pragma unroll
    for (int q = 0; q < 4; ++q) {
      const int g = gh * 4 + q;
      const unsigned short* hc = hb + (q * 2 + cur) * HB;
      f32x4 a0 = {}, a1 = {}, a2 = {}, a3 = {};
      #pragma unroll
      for (int kt = 0; kt < 16; kt += 2) {
        bf16x8 af0 = __builtin_bit_cast(bf16x8, *reinterpret_cast<const u16x8*>(
            &hc[arow * 520 + kt * 32 + aoff]));
        bf16x8 af1 = __builtin_bit_cast(bf16x8, *reinterpret_cast<const u16x8*>(
            &hc[arow * 520 + (kt + 1) * 32 + aoff]));
        a0 = __builtin_amdgcn_mfma_f32_16x16x32_bf16(af0, wfh[kt], a0, 0, 0, 0);
        a1 = __builtin_amdgcn_mfma_f32_16x16x32_bf16(af0, wfl[kt], a1, 0, 0, 0);
        a2 = __builtin_amdgcn_mfma_f32_16x16x32_bf16(af1, wfh[kt + 1], a2, 0, 0, 0);
        a3 = __builtin_amdgcn_mfma_f32_16x16x32_bf16(af1, wfl[kt + 1], a3, 0, 0, 0);
      }
      float hv[4]; unsigned short hu[4];
      #pragma unroll
      for (int r = 0; r < 4; ++r) {
        float z = a0[r] + a1[r] + a2[r] + a3[r] + xpA[q][r];
        float e = __expf(2.0f * z);
        hv[r] = 1.0f - 2.0f / (e + 1.0f);  // tanh(z)
        hu[r] = f2bf(hv[r]);
      }
      const size_t obase = ((size_t)t * B_DIM + g * 16) * H_DIM;
      #pragma unroll
      for (int r = 0; r < 4; ++r)
        out[obase + (size_t)(drow + r) * H_DIM + gcol] = hv[r];
      if (t < L_DIM - 1) {
        u64 pv = (u64)hu[0] | ((u64)hu[1] << 16) | ((u64)hu[2] << 32) | ((u64)hu[3] << 48);
        __hip_atomic_store(gbuf + (((size_t)(buf * 8 + g) * 8 + c) * 256 + pslot), pv,
                           __ATOMIC_RELAXED, __HIP_MEMORY_SCOPE_AGENT);
        unsigned short* hn = hb + (q * 2 + nxt) * HB;
        #pragma unroll
        for (int r = 0; r < 4; ++r)
          hn[(drow + r) * 520 + gcol] = hu[r];
      }
    }
    if (t == L_DIM - 1) break;

    // ---- phase 2: ONE deferred ack, then 4 tags ----
    __builtin_amdgcn_sched_barrier(0);
    asm volatile("s_waitcnt vmcnt(0)" ::: "memory");  // all 4 publishes at coherent point
    __builtin_amdgcn_sched_barrier(0);
    if (lane == 0) {
      #pragma unroll
      for (int q = 0; q < 4; ++q)
        __hip_atomic_store(tags + ((size_t)((buf * 8 + gh * 4 + q) * 8 + c)) * 4 + w,
                           step, __ATOMIC_RELAXED, __HIP_MEMORY_SCOPE_AGENT);
    }

    // ---- phase 3: xp advance (t+2); loads fly during poll ----
    #pragma unroll
    for (int q = 0; q < 4; ++q) xpA[q] = xpB[q];
    {
      const int tn = (t + 2 < L_DIM) ? t + 2 : L_DIM - 1;
      #pragma unroll
      for (int q = 0; q < 4; ++q) {
        const size_t obn = ((size_t)tn * B_DIM + (gh * 4 + q) * 16) * H_DIM;
        #pragma unroll
        for (int r = 0; r < 4; ++r)
          xpB[q][r] = out[obn + (size_t)(drow + r) * H_DIM + gcol];
      }
    }

    // ---- phase 4: poll all 28 peer tags in parallel (lane l: q=l/7, si=l%7) ----
    if (lane < 28) {
      int q = lane / 7, si = lane % 7;
      int s = si + (si >= c ? 1 : 0);
      const u32* tp = tags + ((size_t)((buf * 8 + gh * 4 + q) * 8 + s)) * 4 + w;
      while (__hip_atomic_load(tp, __ATOMIC_RELAXED, __HIP_MEMORY_SCOPE_AGENT) < step) {}
    }
    __builtin_amdgcn_sched_barrier(0);
    asm volatile("" ::: "memory");

    // ---- phase 5: per-q pull (7 u64) + scatter into hb[q][nxt] ----
    #pragma unroll
    for (int q = 0; q < 4; ++q) {
      const int g = gh * 4 + q;
      unsigned short* hn = hb + (q * 2 + nxt) * HB;
      u64 pul[7];
      #pragma unroll
      for (int si = 0; si < 7; ++si) {
        int s = si + (si >= c ? 1 : 0);
        pul[si] = __hip_atomic_load(gbuf + (((size_t)(buf * 8 + g) * 8 + s) * 256 + tid),
                                    __ATOMIC_RELAXED, __HIP_MEMORY_SCOPE_AGENT);
      }
      #pragma unroll
      for (int si = 0; si < 7; ++si) {
        int s = si + (si >= c ? 1 : 0);
        #pragma unroll
        for (int dr = 0; dr < 4; ++dr)
          hn[(crow0 + dr) * 520 + s * 64 + ccol] = (unsigned short)(pul[si] >> (16 * dr));
      }
    }
    __builtin_amdgcn_sched_barrier(0);
    asm volatile("s_waitcnt lgkmcnt(0)" ::: "memory");
    __builtin_amdgcn_sched_barrier(0);
    __builtin_amdgcn_s_barrier();      // all hb[*][nxt] = h_{t+1}; 1 barrier/step
    __builtin_amdgcn_sched_barrier(0);
  }
}

extern "C" void kernel_launch(void* const* d_in, const int* in_sizes, int n_in,
                              void* d_out, int out_size, void* d_ws, size_t ws_size,
                              hipStream_t stream) {
  (void)in_sizes; (void)n_in; (void)out_size; (void)ws_size;
  const float* x  = (const float*)d_in[0];
  const float* h0 = (const float*)d_in[1];
  const float* Wx = (const float*)d_in[2];
  const float* Wh = (const float*)d_in[3];
  const float* bh = (const float*)d_in[4];
  float* out = (float*)d_out;

  unsigned short* WxHi = (unsigned short*)d_ws;       // 131072 u16
  unsigned short* WxLo = WxHi + 131072;               // 131072 u16
  unsigned short* WhHi = WxLo + 131072;               // 262144 u16
  unsigned short* WhLo = WhHi + 262144;               // 262144 u16 (ends 1572864 B)
  unsigned int*   tags = (unsigned int*)((char*)d_ws + 1572864);  // 512 u32 = 2 KB
  u64*            gbuf = (u64*)((char*)d_ws + 1575936);           // 32768 u64 = 256 KB

  // per-launch: zero tags (deterministic under graph replay)
  hipMemsetAsync(tags, 0, 2048, stream);

  // raise dynamic-LDS cap for the 133 KB h buffers (host-side, capture-safe;
  // idempotent — R2 precedent passed graph capture)
  hipFuncSetAttribute(reinterpret_cast<const void*>(rnn_kernel),
                      hipFuncAttributeMaxDynamicSharedMemorySize, 133120);

  hipLaunchKernelGGL(pack_weights, dim3(128), dim3(256), 0, stream,
                     Wx, Wh, WxHi, WxLo, WhHi, WhLo);
  hipLaunchKernelGGL(xproj_kernel, dim3(1024, 4), dim3(256), 0, stream,
                     x, WxHi, WxLo, bh, out);
  hipLaunchKernelGGL(rnn_kernel, dim3(16), dim3(256), 133120, stream,
                     h0, WhHi, WhLo, tags, gbuf, out);
}